// Round 1
// 124.550 us; speedup vs baseline: 1.0219x; 1.0219x over previous
//
#include <hip/hip_runtime.h>
#include <math.h>

// PCNN recurrence, wave-synchronous v4 (DPP exchange).
// One WAVE owns R=256 region elems (C=128 stored + 64-halo each side, halo>=T
// so waves are independent — no barriers, no LDS). Lane i holds region elems
// {2i,2i+1} (slot0) and {128+2i,128+2i+1} (slot1) as float2.
// v4 changes vs v3 (44us/dispatch, VALUBusy 53% CU-level = ~14% per-SIMD,
// HBM 32% -> latency-bound on the serial step chain):
//  - neighbor exchange via DPP wave_shr:1/wave_shl:1 (VALU pipe, ~4cyc)
//    instead of 4x ds_bpermute + lgkmcnt (~120cyc LDS round-trip injected
//    into all 64 serial steps). Cross-slot lane fixes via v_readlane.
//  - DPP bound_ctrl=0 provides the region-edge zero for free (2 fewer
//    cndmasks than the bpermute wrap-fix needed).
//  - boundary predication moved off the chain: OOB elems get e=+inf once,
//    so sigmoid(u-e)=sigmoid(-inf)=0 exactly (exp->inf, rcp->0); the 4
//    per-step vz cndmasks are gone.
//  - x prefetch ring deepened 8 -> 16 (32 loads in flight; VGPR ~44->~105,
//    free at 8 waves/CU which is grid-limited anyway).

#define TT 64
#define LL 8192
#define CC 128
#define HH 64
#define NCHUNK 64   // LL / CC
#define DEPTH 16

typedef float v2f __attribute__((ext_vector_type(2)));

__device__ __forceinline__ float dpp_shr1(float v) {
    // lane i <- lane i-1; lane 0 <- 0 (bound_ctrl). DPP_CTRL WAVE_SHR1=0x138.
    return __int_as_float(__builtin_amdgcn_update_dpp(
        0, __float_as_int(v), 0x138, 0xF, 0xF, true));
}
__device__ __forceinline__ float dpp_shl1(float v) {
    // lane i <- lane i+1; lane 63 <- 0 (bound_ctrl). DPP_CTRL WAVE_SHL1=0x130.
    return __int_as_float(__builtin_amdgcn_update_dpp(
        0, __float_as_int(v), 0x130, 0xF, 0xF, true));
}
__device__ __forceinline__ float rdlane(float v, int l) {
    return __int_as_float(__builtin_amdgcn_readlane(__float_as_int(v), l));
}
__device__ __forceinline__ float fsigmoid(float z) {
    return __fdividef(1.0f, 1.0f + __expf(-z));
}

__global__ __launch_bounds__(256) void pcnn5_kernel(
    const float* __restrict__ x, const float* __restrict__ wptr,
    float* __restrict__ out)
{
    const int lane = threadIdx.x & 63;
    const int tile = blockIdx.x * 4 + (threadIdx.x >> 6);  // 2048 wave-tiles
    const int chunk = tile & (NCHUNK - 1);
    const int b     = tile >> 6;

    const float w0 = wptr[0], w1 = wptr[1], w2 = wptr[2];
    const float df = 0.90483741803595957f;  // exp(-0.1)
    const float dl = 0.36787944117144233f;  // exp(-1)
    const float de = 0.36787944117144233f;

    const int r0 = 2 * lane;                 // slot0 region idx; slot1 = r0+128
    const int c0 = chunk * CC - HH + r0;     // global col, slot0
    const int c1 = c0 + 128;                 // global col, slot1
    const bool vz0 = ((unsigned)c0 < (unsigned)LL);
    const bool vz1 = ((unsigned)c1 < (unsigned)LL);
    const int cc0 = min(max(c0, 0), LL - 2); // clamped (always-safe) load cols
    const int cc1 = min(max(c1, 0), LL - 2);

    const float* xbase = x + (size_t)b * TT * LL;
    const float* xp0 = xbase + cc0;
    const float* xp1 = xbase + cc1;

    // merged store: lanes 0..31 write slot1 (cols chunk*128+64+2lane),
    // lanes 32..63 write slot0 (cols chunk*128+2(lane-32)) — one contiguous
    // 512B segment, always in-bounds, unconditional.
    const bool lo = (lane < 32);
    float* op = out + (size_t)b * TT * LL + (lo ? c1 : c0);

    const bool is0  = (lane == 0);
    const bool is63 = (lane == 63);

    // 16-deep prefetch ring: rows t..t+15 (compile-time indices only)
    v2f p0[DEPTH], p1[DEPTH];
    #pragma unroll
    for (int j = 0; j < DEPTH; ++j) {
        p0[j] = *(const v2f*)(xp0 + (size_t)j * LL);
        p1[j] = *(const v2f*)(xp1 + (size_t)j * LL);
    }

    const float INF = __builtin_inff();
    v2f f0 = {0.f, 0.f}, f1 = {0.f, 0.f};
    v2f l0 = {0.f, 0.f}, l1 = {0.f, 0.f};
    // OOB elems: e=+inf forever -> u-e=-inf -> sigmoid=0 exactly, no per-step
    // predication needed (exp(+inf)=inf, rcp(inf)=0; e stays inf under
    // e=de*e+10*y).
    v2f e0, e1;
    e0.x = vz0 ? 10.f : INF;  e0.y = e0.x;
    e1.x = vz1 ? 10.f : INF;  e1.y = e1.x;
    v2f y0 = {0.f, 0.f}, y1 = {0.f, 0.f};

    auto step = [&](v2f xa, v2f xb) {
        // neighbor exchange (old y) — pure VALU, no LDS pipe:
        float yl0 = dpp_shr1(y0.y);                       // lane0 -> 0 = region edge
        float rl1 = dpp_shr1(y1.y);
        float yl1 = is0 ? rdlane(y0.y, 63) : rl1;         // slot1 left of lane0 = slot0 ln63.y
        float rr0 = dpp_shl1(y0.x);
        float yr0 = is63 ? rdlane(y1.x, 0) : rr0;         // slot0 right of lane63 = slot1 ln0.x
        float yr1 = dpp_shl1(y1.x);                       // lane63 -> 0 = region edge

        f0.x = df * f0.x + xa.x + (w0 * yl0  + w1 * y0.x + w2 * y0.y);
        f0.y = df * f0.y + xa.y + (w0 * y0.x + w1 * y0.y + w2 * yr0);
        f1.x = df * f1.x + xb.x + (w0 * yl1  + w1 * y1.x + w2 * y1.y);
        f1.y = df * f1.y + xb.y + (w0 * y1.x + w1 * y1.y + w2 * yr1);
        l0.x = dl * l0.x + (yl0  + y0.y);
        l0.y = dl * l0.y + (y0.x + yr0);
        l1.x = dl * l1.x + (yl1  + y1.y);
        l1.y = dl * l1.y + (y1.x + yr1);
        float u00 = f0.x * (1.0f + 0.5f * l0.x);
        float u01 = f0.y * (1.0f + 0.5f * l0.y);
        float u10 = f1.x * (1.0f + 0.5f * l1.x);
        float u11 = f1.y * (1.0f + 0.5f * l1.y);
        e0.x = de * e0.x + 10.0f * y0.x;
        e0.y = de * e0.y + 10.0f * y0.y;
        e1.x = de * e1.x + 10.0f * y1.x;
        e1.y = de * e1.y + 10.0f * y1.y;
        y0.x = fsigmoid(u00 - e0.x);
        y0.y = fsigmoid(u01 - e0.y);
        y1.x = fsigmoid(u10 - e1.x);
        y1.y = fsigmoid(u11 - e1.y);

        v2f yst;
        yst.x = lo ? y1.x : y0.x;
        yst.y = lo ? y1.y : y0.y;
        *(v2f*)op = yst;
        op += LL;
    };

    const float* xl0 = xp0 + DEPTH * (size_t)LL;  // row t+DEPTH at loop top
    const float* xl1 = xp1 + DEPTH * (size_t)LL;

    for (int t = 0; t < TT; t += DEPTH) {
        // loads in this iteration target rows t+DEPTH..t+2*DEPTH-1; valid iff
        // t+2*DEPTH <= TT. Last outer iteration: redirect to row 0 with
        // stride 0 (same dummy address -> cache-resident, never consumed).
        const bool live = (t + 2 * DEPTH <= TT);
        const float*  a0 = live ? xl0 : xp0;
        const float*  a1 = live ? xl1 : xp1;
        const size_t st  = live ? (size_t)LL : 0;
        #pragma unroll
        for (int j = 0; j < DEPTH; ++j) {
            step(p0[j], p1[j]);
            p0[j] = *(const v2f*)(a0 + (size_t)j * st);
            p1[j] = *(const v2f*)(a1 + (size_t)j * st);
        }
        xl0 += DEPTH * (size_t)LL;
        xl1 += DEPTH * (size_t)LL;
    }
}

extern "C" void kernel_launch(void* const* d_in, const int* in_sizes, int n_in,
                              void* d_out, int out_size, void* d_ws, size_t ws_size,
                              hipStream_t stream) {
    const float* x = (const float*)d_in[0];
    const float* w = (const float*)d_in[1];
    float* out = (float*)d_out;
    // 2048 wave-tiles = 512 blocks x 4 waves; no LDS, no barriers.
    pcnn5_kernel<<<dim3(512), dim3(256), 0, stream>>>(x, w, out);
}

// Round 2
// 122.233 us; speedup vs baseline: 1.0412x; 1.0190x over previous
//
#include <hip/hip_runtime.h>
#include <math.h>

// PCNN recurrence, wave-synchronous v5 (pinned prefetch ring).
// One WAVE owns R=256 region elems (C=128 stored + 64-halo each side, halo>=T
// so waves are independent — no barriers, no LDS). Lane i holds region elems
// {2i,2i+1} (slot0) and {128+2i,128+2i+1} (slot1) as float2.
// v5 theory (from v4 post-mortem): VGPR_Count=56 proves the compiler SANK the
// "prefetch ring" loads to their uses (x/out are __restrict__, no barriers ->
// sinking is legal and reduces pressure). Every step was eating a full L2/L3
// load round-trip (~200-700cyc) ON the serial chain: 1650 cyc/step wall vs
// ~300 issue. Fix:
//  - x loads issued via asm volatile global_load_dwordx2 (cannot be sunk
//    across the memory-clobber waits) -> ring of DEPTH=8 is now real.
//  - explicit counted s_waitcnt vmcnt(14) + sched_barrier(0) at step top
//    (guide rule #18: reg-only uses otherwise hoist past inline-asm waits).
//    Per step VMEM = 1 store + 2 loads, all pinned between waits, so counts
//    are deterministic; <=14 guarantees this step's load pair retired, incl.
//    at cold start (16 outstanding). Never drains to 0 in the loop.
//  - DPP exchange kept from v4 (neutral now, should matter once loads hide).

#define TT 64
#define LL 8192
#define CC 128
#define HH 64
#define NCHUNK 64   // LL / CC
#define DEPTH 8

typedef float v2f __attribute__((ext_vector_type(2)));

__device__ __forceinline__ float dpp_shr1(float v) {
    // lane i <- lane i-1; lane 0 <- 0 (bound_ctrl). DPP_CTRL WAVE_SHR1=0x138.
    return __int_as_float(__builtin_amdgcn_update_dpp(
        0, __float_as_int(v), 0x138, 0xF, 0xF, true));
}
__device__ __forceinline__ float dpp_shl1(float v) {
    // lane i <- lane i+1; lane 63 <- 0 (bound_ctrl). DPP_CTRL WAVE_SHL1=0x130.
    return __int_as_float(__builtin_amdgcn_update_dpp(
        0, __float_as_int(v), 0x130, 0xF, 0xF, true));
}
__device__ __forceinline__ float rdlane(float v, int l) {
    return __int_as_float(__builtin_amdgcn_readlane(__float_as_int(v), l));
}
__device__ __forceinline__ float fsigmoid(float z) {
    return __fdividef(1.0f, 1.0f + __expf(-z));
}
// Pinned 8B load: volatile asm cannot be sunk past the memory-clobbered
// waitcnt asm below, so the prefetch distance is structural, not a request.
__device__ __forceinline__ v2f gload2(const float* p) {
    v2f r;
    asm volatile("global_load_dwordx2 %0, %1, off"
                 : "=v"(r) : "v"(p) : "memory");
    return r;
}
__device__ __forceinline__ void wait_ring() {
    // <=14 outstanding: youngest 14 = ~5 newest load pairs + 4 newest stores;
    // retires this step's pair (and stores >=4 steps old). Also correct at
    // cold start (prologue leaves 16 loads outstanding -> waits for pair 0).
    asm volatile("s_waitcnt vmcnt(14)" ::: "memory");
    __builtin_amdgcn_sched_barrier(0);
}

__global__ __launch_bounds__(256) void pcnn6_kernel(
    const float* __restrict__ x, const float* __restrict__ wptr,
    float* __restrict__ out)
{
    const int lane = threadIdx.x & 63;
    const int tile = blockIdx.x * 4 + (threadIdx.x >> 6);  // 2048 wave-tiles
    const int chunk = tile & (NCHUNK - 1);
    const int b     = tile >> 6;

    const float w0 = wptr[0], w1 = wptr[1], w2 = wptr[2];
    const float df = 0.90483741803595957f;  // exp(-0.1)
    const float dl = 0.36787944117144233f;  // exp(-1)
    const float de = 0.36787944117144233f;

    const int r0 = 2 * lane;                 // slot0 region idx; slot1 = r0+128
    const int c0 = chunk * CC - HH + r0;     // global col, slot0
    const int c1 = c0 + 128;                 // global col, slot1
    const bool vz0 = ((unsigned)c0 < (unsigned)LL);
    const bool vz1 = ((unsigned)c1 < (unsigned)LL);
    const int cc0 = min(max(c0, 0), LL - 2); // clamped (always-safe) load cols
    const int cc1 = min(max(c1, 0), LL - 2);

    const float* xbase = x + (size_t)b * TT * LL;
    const float* xp0 = xbase + cc0;
    const float* xp1 = xbase + cc1;

    // merged store: lanes 0..31 write slot1 (cols chunk*128+64+2lane),
    // lanes 32..63 write slot0 (cols chunk*128+2(lane-32)) — one contiguous
    // 512B segment, always in-bounds, unconditional.
    const bool lo = (lane < 32);
    float* op = out + (size_t)b * TT * LL + (lo ? c1 : c0);

    const bool is0  = (lane == 0);
    const bool is63 = (lane == 63);

    // DEPTH-deep prefetch ring, pinned in registers by asm issue.
    v2f p0[DEPTH], p1[DEPTH];
    #pragma unroll
    for (int j = 0; j < DEPTH; ++j) {
        p0[j] = gload2(xp0 + (size_t)j * LL);
        p1[j] = gload2(xp1 + (size_t)j * LL);
    }

    const float INF = __builtin_inff();
    v2f f0 = {0.f, 0.f}, f1 = {0.f, 0.f};
    v2f l0 = {0.f, 0.f}, l1 = {0.f, 0.f};
    // OOB elems: e=+inf forever -> sigmoid(u-e)=0 exactly; no per-step
    // predication (exp(+inf)=inf, rcp(inf)=0; e stays inf under de*e+10*y).
    v2f e0, e1;
    e0.x = vz0 ? 10.f : INF;  e0.y = e0.x;
    e1.x = vz1 ? 10.f : INF;  e1.y = e1.x;
    v2f y0 = {0.f, 0.f}, y1 = {0.f, 0.f};

    auto step = [&](v2f xa, v2f xb) {
        // neighbor exchange (old y) — pure VALU, no LDS pipe:
        float yl0 = dpp_shr1(y0.y);                       // lane0 -> 0 = region edge
        float rl1 = dpp_shr1(y1.y);
        float yl1 = is0 ? rdlane(y0.y, 63) : rl1;         // slot1 left of lane0 = slot0 ln63.y
        float rr0 = dpp_shl1(y0.x);
        float yr0 = is63 ? rdlane(y1.x, 0) : rr0;         // slot0 right of lane63 = slot1 ln0.x
        float yr1 = dpp_shl1(y1.x);                       // lane63 -> 0 = region edge

        f0.x = df * f0.x + xa.x + (w0 * yl0  + w1 * y0.x + w2 * y0.y);
        f0.y = df * f0.y + xa.y + (w0 * y0.x + w1 * y0.y + w2 * yr0);
        f1.x = df * f1.x + xb.x + (w0 * yl1  + w1 * y1.x + w2 * y1.y);
        f1.y = df * f1.y + xb.y + (w0 * y1.x + w1 * y1.y + w2 * yr1);
        l0.x = dl * l0.x + (yl0  + y0.y);
        l0.y = dl * l0.y + (y0.x + yr0);
        l1.x = dl * l1.x + (yl1  + y1.y);
        l1.y = dl * l1.y + (y1.x + yr1);
        float u00 = f0.x * (1.0f + 0.5f * l0.x);
        float u01 = f0.y * (1.0f + 0.5f * l0.y);
        float u10 = f1.x * (1.0f + 0.5f * l1.x);
        float u11 = f1.y * (1.0f + 0.5f * l1.y);
        e0.x = de * e0.x + 10.0f * y0.x;
        e0.y = de * e0.y + 10.0f * y0.y;
        e1.x = de * e1.x + 10.0f * y1.x;
        e1.y = de * e1.y + 10.0f * y1.y;
        y0.x = fsigmoid(u00 - e0.x);
        y0.y = fsigmoid(u01 - e0.y);
        y1.x = fsigmoid(u10 - e1.x);
        y1.y = fsigmoid(u11 - e1.y);

        v2f yst;
        yst.x = lo ? y1.x : y0.x;
        yst.y = lo ? y1.y : y0.y;
        *(v2f*)op = yst;   // plain store: pinned between memory-clobber asms
        op += LL;
    };

    const float* xl0 = xp0 + DEPTH * (size_t)LL;  // row t+DEPTH at loop top
    const float* xl1 = xp1 + DEPTH * (size_t)LL;

    for (int t = 0; t < TT; t += DEPTH) {
        // loads in this iteration target rows t+DEPTH..t+2*DEPTH-1; valid iff
        // t+2*DEPTH <= TT. Last outer iteration: redirect to the base row with
        // stride 0 (dummy, cache-hot, never consumed) to keep VMEM counts
        // uniform for the counted waits.
        const bool live = (t + 2 * DEPTH <= TT);
        const float*  a0 = live ? xl0 : xp0;
        const float*  a1 = live ? xl1 : xp1;
        const size_t st  = live ? (size_t)LL : 0;
        #pragma unroll
        for (int j = 0; j < DEPTH; ++j) {
            wait_ring();                    // this step's pair is now in regs
            step(p0[j], p1[j]);             // compute + 1 store
            p0[j] = gload2(a0 + (size_t)j * st);   // refill: rows t+DEPTH+j
            p1[j] = gload2(a1 + (size_t)j * st);
        }
        xl0 += DEPTH * (size_t)LL;
        xl1 += DEPTH * (size_t)LL;
    }
}

extern "C" void kernel_launch(void* const* d_in, const int* in_sizes, int n_in,
                              void* d_out, int out_size, void* d_ws, size_t ws_size,
                              hipStream_t stream) {
    const float* x = (const float*)d_in[0];
    const float* w = (const float*)d_in[1];
    float* out = (float*)d_out;
    // 2048 wave-tiles = 512 blocks x 4 waves; no LDS, no barriers.
    pcnn6_kernel<<<dim3(512), dim3(256), 0, stream>>>(x, w, out);
}

// Round 3
// 121.618 us; speedup vs baseline: 1.0465x; 1.0051x over previous
//
#include <hip/hip_runtime.h>
#include <math.h>

// PCNN recurrence, wave-synchronous v6 (packed-f32 + saddr addressing).
// One WAVE owns R=256 region elems (C=128 stored + 64-halo each side, halo>=T
// so waves are independent — no barriers, no LDS). Lane i holds region elems
// {2i,2i+1} (slot0) and {128+2i,128+2i+1} (slot1) as float2.
// v6 theory (from v5 post-mortem): counted-vmcnt ring made load latency
// irrelevant (~7000cyc slack) yet step still ~1550cyc -> ISSUE-bound at
// 2 waves/SIMD. Cut instructions per step:
//  - state math written as v2f VECTOR expressions so ISel forms full-rate
//    v_pk_fma_f32/v_pk_add_f32/v_pk_mul_f32 (scalar .x/.y form blocked it).
//  - all VMEM via SGPR-base + 32-bit voffset asm (global_*_dwordx2 v,s[b]):
//    per-step addr math = 3x v_add_u32 instead of ~10 64-bit mads. Bases
//    made provably wave-uniform via readfirstlane.
//  - counted s_waitcnt vmcnt(14) + sched_barrier(0) per step kept (1 store +
//    2 loads per step; never drains to 0). DPP exchange kept.

#define TT 64
#define LL 8192
#define CC 128
#define HH 64
#define NCHUNK 64   // LL / CC
#define DEPTH 8
#define ROWB (LL * 4)  // 32768 B row stride

typedef float v2f __attribute__((ext_vector_type(2)));

__device__ __forceinline__ float dpp_shr1(float v) {
    // lane i <- lane i-1; lane 0 <- 0 (bound_ctrl). WAVE_SHR1=0x138.
    return __int_as_float(__builtin_amdgcn_update_dpp(
        0, __float_as_int(v), 0x138, 0xF, 0xF, true));
}
__device__ __forceinline__ float dpp_shl1(float v) {
    // lane i <- lane i+1; lane 63 <- 0 (bound_ctrl). WAVE_SHL1=0x130.
    return __int_as_float(__builtin_amdgcn_update_dpp(
        0, __float_as_int(v), 0x130, 0xF, 0xF, true));
}
__device__ __forceinline__ float rdlane(float v, int l) {
    return __int_as_float(__builtin_amdgcn_readlane(__float_as_int(v), l));
}
__device__ __forceinline__ float fsig_neg(float z) {
    // sigmoid(u-e) with z = e-u:  1/(1+exp(z)). z=+inf -> 0 exactly.
    return __fdividef(1.0f, 1.0f + __expf(z));
}
// Pinned VMEM: SGPR base + 32-bit unsigned voffset. volatile asm keeps issue
// order structural; counted waits below are the only synchronization.
__device__ __forceinline__ v2f gload2(const float* sb, int voff) {
    v2f r;
    asm volatile("global_load_dwordx2 %0, %1, %2"
                 : "=v"(r) : "v"(voff), "s"(sb) : "memory");
    return r;
}
__device__ __forceinline__ void gstore2(float* sb, int voff, v2f d) {
    asm volatile("global_store_dwordx2 %0, %1, %2"
                 :: "v"(voff), "v"(d), "s"(sb) : "memory");
}
__device__ __forceinline__ void wait14() {
    // per step: 1 store + 2 loads issued. <=14 outstanding guarantees this
    // step's ring pair (issued 24 vmem ops ago) retired; never drains to 0.
    asm volatile("s_waitcnt vmcnt(14)" ::: "memory");
    __builtin_amdgcn_sched_barrier(0);
}

__global__ __launch_bounds__(256) void pcnn7_kernel(
    const float* __restrict__ x, const float* __restrict__ wptr,
    float* __restrict__ out)
{
    const int lane = threadIdx.x & 63;
    const int tile = blockIdx.x * 4 + (threadIdx.x >> 6);  // 2048 wave-tiles
    const int chunk = tile & (NCHUNK - 1);
    const int b     = tile >> 6;

    const float w0 = wptr[0], w1 = wptr[1], w2 = wptr[2];
    const float df = 0.90483741803595957f;  // exp(-0.1)
    const float dl = 0.36787944117144233f;  // exp(-1)
    const float de = 0.36787944117144233f;

    const int r0 = 2 * lane;                 // slot0 region idx; slot1 = r0+128
    const int c0 = chunk * CC - HH + r0;     // global col, slot0
    const int c1 = c0 + 128;                 // global col, slot1
    const bool vz0 = ((unsigned)c0 < (unsigned)LL);
    const bool vz1 = ((unsigned)c1 < (unsigned)LL);
    const int cc0 = min(max(c0, 0), LL - 2); // clamped (always-safe) load cols
    const int cc1 = min(max(c1, 0), LL - 2);

    // wave-uniform batch base, forced into SGPRs for saddr-form VMEM
    const int boff = __builtin_amdgcn_readfirstlane(b * (TT * LL));
    const float* xb = x + boff;
    float* outb = out + boff;

    // merged store: lanes 0..31 write slot1, lanes 32..63 slot0 — one
    // contiguous 512B segment per wave per row, always in-bounds.
    const bool lo = (lane < 32);
    int vo = (lo ? c1 : c0) * 4;             // store voffset (bytes)

    const bool is0  = (lane == 0);
    const bool is63 = (lane == 63);

    const int vx0 = cc0 * 4, vx1 = cc1 * 4;  // load voffsets, row 0

    // DEPTH-deep prefetch ring, pinned by asm issue.
    v2f p0[DEPTH], p1[DEPTH];
    #pragma unroll
    for (int j = 0; j < DEPTH; ++j) {
        p0[j] = gload2(xb, vx0 + j * ROWB);
        p1[j] = gload2(xb, vx1 + j * ROWB);
    }
    int r0off = vx0 + DEPTH * ROWB;          // next refill row voffsets
    int r1off = vx1 + DEPTH * ROWB;

    const float INF = __builtin_inff();
    v2f f0 = {0.f, 0.f}, f1 = {0.f, 0.f};
    v2f l0 = {0.f, 0.f}, l1 = {0.f, 0.f};
    // OOB elems: e=+inf forever -> sigmoid arg +inf -> y=0 exactly; no
    // per-step predication (exp(inf)=inf, rcp(inf)=0; e stays inf).
    v2f e0, e1;
    e0.x = vz0 ? 10.f : INF;  e0.y = e0.x;
    e1.x = vz1 ? 10.f : INF;  e1.y = e1.x;
    v2f y0 = {0.f, 0.f}, y1 = {0.f, 0.f};

    for (int t = 0; t < TT; t += DEPTH) {
        // refills this iter target rows t+8..t+15; valid iff t+16 <= TT.
        // Last iter: redirect to row 0 (in-bounds dummy, never consumed),
        // keeping VMEM counts uniform for the counted waits.
        const bool live = (t + 2 * DEPTH <= TT);
        const int adv = live ? ROWB : 0;
        if (!live) { r0off = vx0; r1off = vx1; }
        #pragma unroll
        for (int j = 0; j < DEPTH; ++j) {
            wait14();                         // ring pair j now in registers
            const v2f xa = p0[j], xc = p1[j];

            // neighbor exchange (old y) — pure VALU:
            float yl0 = dpp_shr1(y0.y);                // lane0 -> 0 (edge)
            float rl1 = dpp_shr1(y1.y);
            float yl1 = is0 ? rdlane(y0.y, 63) : rl1;  // slot1 left of ln0
            float rr0 = dpp_shl1(y0.x);
            float yr0 = is63 ? rdlane(y1.x, 0) : rr0;  // slot0 right of ln63
            float yr1 = dpp_shl1(y1.x);                // lane63 -> 0 (edge)

            // shifted vectors: sl = left neighbors, sr = right neighbors
            v2f sl0 = {yl0, y0.x}, sr0 = {y0.y, yr0};
            v2f sl1 = {yl1, y1.x}, sr1 = {y1.y, yr1};

            // vector-typed state math -> v_pk_* formation
            f0 = df * f0 + xa + (w0 * sl0 + w1 * y0 + w2 * sr0);
            f1 = df * f1 + xc + (w0 * sl1 + w1 * y1 + w2 * sr1);
            l0 = dl * l0 + (sl0 + sr0);
            l1 = dl * l1 + (sl1 + sr1);
            v2f u0 = f0 * (1.0f + 0.5f * l0);
            v2f u1 = f1 * (1.0f + 0.5f * l1);
            e0 = de * e0 + 10.0f * y0;
            e1 = de * e1 + 10.0f * y1;
            v2f z0 = e0 - u0;                 // sigmoid(u-e) = 1/(1+exp(z))
            v2f z1 = e1 - u1;
            y0.x = fsig_neg(z0.x);
            y0.y = fsig_neg(z0.y);
            y1.x = fsig_neg(z1.x);
            y1.y = fsig_neg(z1.y);

            v2f yst;
            yst.x = lo ? y1.x : y0.x;
            yst.y = lo ? y1.y : y0.y;
            gstore2(outb, vo, yst);
            vo += ROWB;

            p0[j] = gload2(xb, r0off);        // refill rows t+8+j
            p1[j] = gload2(xb, r1off);
            r0off += adv;
            r1off += adv;
        }
    }
}

extern "C" void kernel_launch(void* const* d_in, const int* in_sizes, int n_in,
                              void* d_out, int out_size, void* d_ws, size_t ws_size,
                              hipStream_t stream) {
    const float* x = (const float*)d_in[0];
    const float* w = (const float*)d_in[1];
    float* out = (float*)d_out;
    // 2048 wave-tiles = 512 blocks x 4 waves; no LDS, no barriers.
    pcnn7_kernel<<<dim3(512), dim3(256), 0, stream>>>(x, w, out);
}

// Round 4
// 121.422 us; speedup vs baseline: 1.0482x; 1.0016x over previous
//
#include <hip/hip_runtime.h>
#include <math.h>

// PCNN recurrence, wave-synchronous v7 (deep wait slack).
// One WAVE owns R=256 region elems (C=128 stored + 64-halo each side, halo>=T
// so waves are independent — no barriers, no LDS). Lane i holds region elems
// {2i,2i+1} (slot0) and {128+2i,128+2i+1} (slot1) as float2.
//
// v7 theory (from v4-v6 post-mortems, all ~flat at 42-44us): NOT issue-bound
// (packed math: no change), NOT load-latency-bound (pinned ring: no change).
// The common gate: every version's per-step wait forces retirement of ops
// only ~2.3 steps old in the shared in-order vmcnt FIFO — INCLUDING the
// store issued ~2 steps ago. Store-ack under write congestion ~3k cyc ->
// step ~ ack/2.3 ~ 1450 cyc -> 64 steps ~ 39us. Matches all versions.
// Fix: maximize slack. DEPTH=16 ring; steady wait vmcnt(45) (a ring pair has
// exactly 45 younger VMEM ops at its use: 15 steps x 3). Cold start via a
// PEELED first 16 steps with ramped waits vmcnt(30+j) (after the 32-load
// prologue, pair j has 30+j younger ops) instead of over-tightening.
// Stores now retire at age ~15 steps (>5000 cyc) — never on the chain.

#define TT 64
#define LL 8192
#define CC 128
#define HH 64
#define NCHUNK 64   // LL / CC
#define DEPTH 16
#define ROWB (LL * 4)  // 32768 B row stride

typedef float v2f __attribute__((ext_vector_type(2)));

__device__ __forceinline__ float dpp_shr1(float v) {
    // lane i <- lane i-1; lane 0 <- 0 (bound_ctrl). WAVE_SHR1=0x138.
    return __int_as_float(__builtin_amdgcn_update_dpp(
        0, __float_as_int(v), 0x138, 0xF, 0xF, true));
}
__device__ __forceinline__ float dpp_shl1(float v) {
    // lane i <- lane i+1; lane 63 <- 0 (bound_ctrl). WAVE_SHL1=0x130.
    return __int_as_float(__builtin_amdgcn_update_dpp(
        0, __float_as_int(v), 0x130, 0xF, 0xF, true));
}
__device__ __forceinline__ float rdlane(float v, int l) {
    return __int_as_float(__builtin_amdgcn_readlane(__float_as_int(v), l));
}
__device__ __forceinline__ float fsig_neg(float z) {
    // sigmoid(u-e) with z = e-u: 1/(1+exp(z)). z=+inf -> 0 exactly.
    return __fdividef(1.0f, 1.0f + __expf(z));
}
// Pinned VMEM: SGPR base + 32-bit voffset. volatile asm keeps issue order
// structural; the counted waits below are the only synchronization.
__device__ __forceinline__ v2f gload2(const float* sb, int voff) {
    v2f r;
    asm volatile("global_load_dwordx2 %0, %1, %2"
                 : "=v"(r) : "v"(voff), "s"(sb) : "memory");
    return r;
}
__device__ __forceinline__ void gstore2(float* sb, int voff, v2f d) {
    asm volatile("global_store_dwordx2 %0, %1, %2"
                 :: "v"(voff), "v"(d), "s"(sb) : "memory");
}
// Counted wait with literal immediate; sched_barrier stops reg-only compute
// from hoisting above the wait (guide rule #18).
#define WAITV(n) do { \
    asm volatile("s_waitcnt vmcnt(" #n ")" ::: "memory"); \
    __builtin_amdgcn_sched_barrier(0); } while (0)

__global__ __launch_bounds__(256) void pcnn8_kernel(
    const float* __restrict__ x, const float* __restrict__ wptr,
    float* __restrict__ out)
{
    const int lane = threadIdx.x & 63;
    const int tile = blockIdx.x * 4 + (threadIdx.x >> 6);  // 2048 wave-tiles
    const int chunk = tile & (NCHUNK - 1);
    const int b     = tile >> 6;

    const float w0 = wptr[0], w1 = wptr[1], w2 = wptr[2];
    const float df = 0.90483741803595957f;  // exp(-0.1)
    const float dl = 0.36787944117144233f;  // exp(-1)
    const float de = 0.36787944117144233f;

    const int r0 = 2 * lane;                 // slot0 region idx; slot1 = r0+128
    const int c0 = chunk * CC - HH + r0;     // global col, slot0
    const int c1 = c0 + 128;                 // global col, slot1
    const bool vz0 = ((unsigned)c0 < (unsigned)LL);
    const bool vz1 = ((unsigned)c1 < (unsigned)LL);
    const int cc0 = min(max(c0, 0), LL - 2); // clamped (always-safe) load cols
    const int cc1 = min(max(c1, 0), LL - 2);

    // wave-uniform batch base, forced into SGPRs for saddr-form VMEM
    const int boff = __builtin_amdgcn_readfirstlane(b * (TT * LL));
    const float* xb = x + boff;
    float* outb = out + boff;

    // merged store: lanes 0..31 write slot1, lanes 32..63 slot0 — one
    // contiguous 512B segment per wave per row, always in-bounds.
    const bool lo = (lane < 32);
    int vo = (lo ? c1 : c0) * 4;             // store voffset (bytes)

    const bool is0  = (lane == 0);
    const bool is63 = (lane == 63);

    const int vx0 = cc0 * 4, vx1 = cc1 * 4;  // load voffsets, row 0

    // DEPTH=16 prefetch ring, pinned by asm issue. Prologue: 32 loads.
    v2f p0[DEPTH], p1[DEPTH];
    #pragma unroll
    for (int j = 0; j < DEPTH; ++j) {
        p0[j] = gload2(xb, vx0 + j * ROWB);
        p1[j] = gload2(xb, vx1 + j * ROWB);
    }
    int r0off = vx0 + DEPTH * ROWB;          // next refill row voffsets
    int r1off = vx1 + DEPTH * ROWB;
    int adv = ROWB;

    const float INF = __builtin_inff();
    v2f f0 = {0.f, 0.f}, f1 = {0.f, 0.f};
    v2f l0 = {0.f, 0.f}, l1 = {0.f, 0.f};
    // OOB elems: e=+inf forever -> sigmoid arg +inf -> y=0 exactly; no
    // per-step predication (exp(inf)=inf, rcp(inf)=0; e stays inf).
    v2f e0, e1;
    e0.x = vz0 ? 10.f : INF;  e0.y = e0.x;
    e1.x = vz1 ? 10.f : INF;  e1.y = e1.x;
    v2f y0 = {0.f, 0.f}, y1 = {0.f, 0.f};

    auto stepf = [&](v2f xa, v2f xc) {
        // neighbor exchange (old y) — pure VALU:
        float yl0 = dpp_shr1(y0.y);                // lane0 -> 0 (edge)
        float rl1 = dpp_shr1(y1.y);
        float yl1 = is0 ? rdlane(y0.y, 63) : rl1;  // slot1 left of ln0
        float rr0 = dpp_shl1(y0.x);
        float yr0 = is63 ? rdlane(y1.x, 0) : rr0;  // slot0 right of ln63
        float yr1 = dpp_shl1(y1.x);                // lane63 -> 0 (edge)

        v2f sl0 = {yl0, y0.x}, sr0 = {y0.y, yr0};
        v2f sl1 = {yl1, y1.x}, sr1 = {y1.y, yr1};

        // vector-typed state math -> v_pk_* formation
        f0 = df * f0 + xa + (w0 * sl0 + w1 * y0 + w2 * sr0);
        f1 = df * f1 + xc + (w0 * sl1 + w1 * y1 + w2 * sr1);
        l0 = dl * l0 + (sl0 + sr0);
        l1 = dl * l1 + (sl1 + sr1);
        v2f u0 = f0 * (1.0f + 0.5f * l0);
        v2f u1 = f1 * (1.0f + 0.5f * l1);
        e0 = de * e0 + 10.0f * y0;
        e1 = de * e1 + 10.0f * y1;
        v2f z0 = e0 - u0;                 // sigmoid(u-e) = 1/(1+exp(z))
        v2f z1 = e1 - u1;
        y0.x = fsig_neg(z0.x);
        y0.y = fsig_neg(z0.y);
        y1.x = fsig_neg(z1.x);
        y1.y = fsig_neg(z1.y);

        v2f yst;
        yst.x = lo ? y1.x : y0.x;
        yst.y = lo ? y1.y : y0.y;
        gstore2(outb, vo, yst);
        vo += ROWB;
    };

#define STEP(j, W) do { WAITV(W); stepf(p0[j], p1[j]); \
    p0[j] = gload2(xb, r0off); p1[j] = gload2(xb, r1off); \
    r0off += adv; r1off += adv; } while (0)

    // ---- peeled first 16 steps (cold start): ramped waits vmcnt(30+j).
    // After the 32-load prologue, pair j has exactly 30+j younger VMEM ops.
    STEP(0, 30);  STEP(1, 31);  STEP(2, 32);  STEP(3, 33);
    STEP(4, 34);  STEP(5, 35);  STEP(6, 36);  STEP(7, 37);
    STEP(8, 38);  STEP(9, 39);  STEP(10, 40); STEP(11, 41);
    STEP(12, 42); STEP(13, 43); STEP(14, 44); STEP(15, 45);

    // ---- steady state: pair age = 16 steps = 45 younger ops -> vmcnt(45).
    for (int t = DEPTH; t < TT; t += DEPTH) {
        // refills target rows t+16..t+31; last iter (t=48) redirects to row 0
        // (in-bounds dummy, never consumed) keeping VMEM counts uniform.
        if (t + 2 * DEPTH > TT) { r0off = vx0; r1off = vx1; adv = 0; }
        #pragma unroll
        for (int j = 0; j < DEPTH; ++j) {
            WAITV(45);
            stepf(p0[j], p1[j]);
            p0[j] = gload2(xb, r0off);
            p1[j] = gload2(xb, r1off);
            r0off += adv;
            r1off += adv;
        }
    }
    // drain before endpgm (safety; once per wave, negligible)
    asm volatile("s_waitcnt vmcnt(0)" ::: "memory");
}

extern "C" void kernel_launch(void* const* d_in, const int* in_sizes, int n_in,
                              void* d_out, int out_size, void* d_ws, size_t ws_size,
                              hipStream_t stream) {
    const float* x = (const float*)d_in[0];
    const float* w = (const float*)d_in[1];
    float* out = (float*)d_out;
    // 2048 wave-tiles = 512 blocks x 4 waves; no LDS, no barriers.
    pcnn8_kernel<<<dim3(512), dim3(256), 0, stream>>>(x, w, out);
}